// Round 2
// baseline (1622.953 us; speedup 1.0000x reference)
//
#include <hip/hip_runtime.h>
#include <math.h>

// ---------------------------------------------------------------------------
// MemoryEdgeDecoder: B=32,S=512,E=512 -> N=16384 rows, IN=1024, HID=2048,
// OUT=2080 (=32 decoded + 1024 dbl + 1024 ratio), K=10, RATE=0.005.
//
// Pipeline:
//  1. Xb  = bf16(concat(emb_l, emb_r))                      [16384 x 1024]
//  2. W1t/W2t/KW1t = transposed bf16 weights (N x K layout)
//  3. Hb  = relu(Xb @ W1 + b1)          bf16 MFMA GEMM      [16384 x 2048]
//  4. OUT = Hb @ W2 + b2                f32 out             [16384 x 2080]
//  5. postproc: decoded -> d_out, dbl = out*g + prev*(1-g)  (f32 + bf16)
//  6. per k: KH = relu(dbl @ ker_w1[k] + b1k)   bf16 GEMM
//              + fused epilogue GEMV partials: wpart[chunk][row] = KHrow.v_chunk
//            sigma/den from wpart; tpart[sc][b,h] = sum_{s in chunk} sigma*KH
//            agg += (t @ ker_w2[k][:, :1024] + b2k*den)/den   (tiny GEMM)
//     (second einsum eliminated algebraically: S-reduction commutes with W2)
//  7. final: new = dbl*0.995 + agg*0.0005 -> d_out
// ---------------------------------------------------------------------------

typedef __bf16 bf16x8 __attribute__((ext_vector_type(8)));
typedef float  f32x4  __attribute__((ext_vector_type(4)));

__device__ __forceinline__ float bf2f(unsigned short u) {
  unsigned int x = ((unsigned int)u) << 16;
  return __builtin_bit_cast(float, x);
}
__device__ __forceinline__ unsigned short f2bf(float f) {
  unsigned int x = __builtin_bit_cast(unsigned int, f);
  x += 0x7fffu + ((x >> 16) & 1u);   // RNE
  return (unsigned short)(x >> 16);
}
__device__ __forceinline__ void gload_lds16(const void* g, void* l) {
  __builtin_amdgcn_global_load_lds(
      (const __attribute__((address_space(1))) unsigned int*)g,
      (__attribute__((address_space(3))) unsigned int*)l, 16, 0, 0);
}

// ---------------- ws layout (bytes) ----------------
#define OFF_XB    0ull                           // 33,554,432  (reused as dblb)
#define OFF_W1T   (OFF_XB  + 33554432ull)        //  4,194,304
#define OFF_HB    (OFF_W1T + 4194304ull)         // 67,108,864  (reused as dblf)
#define OFF_W2T   (OFF_HB  + 67108864ull)        //  8,912,896  (2176 rows x 2048)
#define OFF_OUT   (OFF_W2T + 8912896ull)         // 136,314,880
// carved out of OUT region after postproc consumed it:
#define OFF_KW1T  OFF_OUT                         // 20,971,520
#define OFF_KH    (OFF_KW1T + 20971520ull)        // 33,554,432
#define OFF_WPART (OFF_KH   + 33554432ull)        //  1,048,576  (16 x 16384 f32)
#define OFF_SIG   (OFF_WPART+ 1048576ull)         //     65,536
#define OFF_DEN   (OFF_SIG  + 65536ull)           //      1,024
#define OFF_TPART (OFF_DEN  + 1024ull)            //  1,048,576  (8 x 32768 f32)
#define OFF_AGG   (OFF_TPART+ 1048576ull)         //    131,072
#define OFF_VBUF  (OFF_AGG  + 131072ull)          //     40,960
// total ws needed: 250,085,376 bytes (~239 MB)

// ---------------- kernels ----------------

// bf16 concat of embeddings: Xb[r][0:512]=el, [512:1024]=er
__global__ void convert_X(const float* __restrict__ el, const float* __restrict__ er,
                          unsigned short* __restrict__ Xb) {
  long gid = (long)blockIdx.x * blockDim.x + threadIdx.x;
  long e = gid * 4;
  long r = e >> 10; int c = (int)(e & 1023);
  const float* s = (c < 512) ? (el + r * 512 + c) : (er + r * 512 + (c - 512));
  float4 v = *(const float4*)s;
  ushort4 o; o.x = f2bf(v.x); o.y = f2bf(v.y); o.z = f2bf(v.z); o.w = f2bf(v.w);
  *(ushort4*)(Xb + e) = o;
}

// f32 (R x C) -> bf16 transposed (C x R). R,C multiples of 32.
__global__ void transpose_cvt(const float* __restrict__ src, unsigned short* __restrict__ dst,
                              int R, int C) {
  __shared__ float tile[32][33];
  long zoff = (long)blockIdx.z * R * C;
  src += zoff; dst += zoff;
  int tx = threadIdx.x, ty = threadIdx.y;           // (32, 8)
  long r0 = (long)blockIdx.y * 32, c0 = (long)blockIdx.x * 32;
#pragma unroll
  for (int j = 0; j < 32; j += 8)
    tile[ty + j][tx] = src[(r0 + ty + j) * C + c0 + tx];
  __syncthreads();
#pragma unroll
  for (int j = 0; j < 32; j += 8)
    dst[(c0 + ty + j) * R + r0 + tx] = f2bf(tile[tx][ty + j]);
}

// m97-style 128x128 bf16 MFMA GEMM. A: M x K (lda=K), Bt: N x K (ldb=K).
// C = act(A@B + bias). WB=1 -> bf16 out, else f32 out. Cols >= Nvalid masked.
// GV=1 (requires Nvalid==ldc==N all valid): additionally emit GEMV partials
//   gout[(blockIdx.y*2+wn)*16384 + row] = sum_{cols of this wave} val*gvec[col]
template <int RELU, int WB, int GV>
__global__ __launch_bounds__(256) void gemm128(
    const unsigned short* __restrict__ A, const unsigned short* __restrict__ Bt,
    const float* __restrict__ bias, unsigned short* __restrict__ Cb,
    float* __restrict__ Cf, const float* __restrict__ gvec,
    float* __restrict__ gout, int K, int Nvalid, int ldc) {
  __shared__ unsigned short As[128 * 32];
  __shared__ unsigned short Bs[128 * 32];
  const int tid = threadIdx.x;
  const int wv = tid >> 6, ln = tid & 63;
  const long m0 = (long)blockIdx.x * 128;
  const long n0 = (long)blockIdx.y * 128;
  const int wm = wv >> 1, wn = wv & 1;
  f32x4 acc[4][4] = {};
  for (int kt = 0; kt < K; kt += 32) {
#pragma unroll
    for (int i = 0; i < 2; ++i) {
      int c = tid + i * 256;                 // chunk id 0..511 (16B each)
      int r = c >> 2, kp = (c & 3) * 8;
      gload_lds16(A + (m0 + r) * K + kt + kp, (void*)&As[(i * 256 + wv * 64) * 8]);
      gload_lds16(Bt + (n0 + r) * K + kt + kp, (void*)&Bs[(i * 256 + wv * 64) * 8]);
    }
    __syncthreads();
    bf16x8 af[4], bfr[4];
#pragma unroll
    for (int mi = 0; mi < 4; ++mi)
      af[mi] = *(const bf16x8*)&As[((wm * 64 + mi * 16 + (ln & 15)) * 4 + (ln >> 4)) * 8];
#pragma unroll
    for (int ni = 0; ni < 4; ++ni)
      bfr[ni] = *(const bf16x8*)&Bs[((wn * 64 + ni * 16 + (ln & 15)) * 4 + (ln >> 4)) * 8];
#pragma unroll
    for (int mi = 0; mi < 4; ++mi)
#pragma unroll
      for (int ni = 0; ni < 4; ++ni)
        acc[mi][ni] = __builtin_amdgcn_mfma_f32_16x16x32_bf16(af[mi], bfr[ni], acc[mi][ni], 0, 0, 0);
    __syncthreads();
  }
  const int lr = ln >> 4, lc = ln & 15;
  long colv[4]; bool okv[4]; float bv[4], gvv[4];
#pragma unroll
  for (int ni = 0; ni < 4; ++ni) {
    colv[ni] = n0 + wn * 64 + ni * 16 + lc;
    okv[ni] = colv[ni] < Nvalid;
    bv[ni] = okv[ni] ? bias[colv[ni]] : 0.f;
    gvv[ni] = GV ? gvec[colv[ni]] : 0.f;
  }
#pragma unroll
  for (int mi = 0; mi < 4; ++mi) {
#pragma unroll
    for (int j = 0; j < 4; ++j) {
      long row = m0 + wm * 64 + mi * 16 + lr * 4 + j;
      float p = 0.f;
#pragma unroll
      for (int ni = 0; ni < 4; ++ni) {
        float v = acc[mi][ni][j] + bv[ni];
        if (RELU) v = fmaxf(v, 0.f);
        if (okv[ni]) {
          if (WB) Cb[row * ldc + colv[ni]] = f2bf(v);
          else    Cf[row * ldc + colv[ni]] = v;
        }
        if (GV) p += v * gvv[ni];
      }
      if (GV) {
#pragma unroll
        for (int off = 1; off < 16; off <<= 1) p += __shfl_xor(p, off);
        if (lc == 0) gout[(blockIdx.y * 2 + wn) * 16384 + row] = p;
      }
    }
  }
}

// decoded -> d_out; dbl = out*g + prev*(1-g) in f32 + bf16
__global__ void postproc(const float* __restrict__ OUT, const float* __restrict__ el,
                         const float* __restrict__ er, float* __restrict__ dec,
                         float* __restrict__ dblf, unsigned short* __restrict__ dblb) {
  long r = blockIdx.x;
  int t = threadIdx.x;
  const float* orow = OUT + r * 2080;
  if (t < 8) {
    float4 v = *(const float4*)(orow + t * 4);
    *(float4*)(dec + r * 32 + t * 4) = v;
  }
  int c = t * 4;
  float4 d  = *(const float4*)(orow + 32 + c);
  float4 rt = *(const float4*)(orow + 1056 + c);
  const float* pp = (c < 512) ? (el + r * 512 + c) : (er + r * 512 + (c - 512));
  float4 p = *(const float4*)pp;
  float4 o; float g;
  g = 1.f / (1.f + expf(-rt.x)); o.x = d.x * g + p.x * (1.f - g);
  g = 1.f / (1.f + expf(-rt.y)); o.y = d.y * g + p.y * (1.f - g);
  g = 1.f / (1.f + expf(-rt.z)); o.z = d.z * g + p.z * (1.f - g);
  g = 1.f / (1.f + expf(-rt.w)); o.w = d.w * g + p.w * (1.f - g);
  *(float4*)(dblf + r * 1024 + c) = o;
  ushort4 ob; ob.x = f2bf(o.x); ob.y = f2bf(o.y); ob.z = f2bf(o.z); ob.w = f2bf(o.w);
  *(ushort4*)(dblb + r * 1024 + c) = ob;
}

// last column of each ker_w2[k] -> compact vbuf[k][h]
__global__ void extract_v(const float* __restrict__ kw2, float* __restrict__ vbuf) {
  int i = blockIdx.x * 256 + threadIdx.x;  // 0..10239
  int k = i >> 10, h = i & 1023;
  vbuf[i] = kw2[(long)k * 1024 * 1025 + (long)h * 1025 + 1024];
}

// sigma = sigmoid(sum_c wpart[c][row] + last_bias); den[b] = sum_s sigma
__global__ __launch_bounds__(512) void sigma_den(const float* __restrict__ wpart,
                                                 const float* __restrict__ kb2k,
                                                 float* __restrict__ sig, float* __restrict__ den) {
  int b = blockIdx.x, t = threadIdx.x;
  int row = b * 512 + t;
  float x = kb2k[1024];
#pragma unroll
  for (int c = 0; c < 16; ++c) x += wpart[c * 16384 + row];
  float s = 1.f / (1.f + expf(-x));
  sig[row] = s;
  float v = s;
#pragma unroll
  for (int off = 32; off >= 1; off >>= 1) v += __shfl_down(v, off);
  __shared__ float ps[8];
  if ((t & 63) == 0) ps[t >> 6] = v;
  __syncthreads();
  if (t == 0) { float dsum = 0.f; for (int i = 0; i < 8; ++i) dsum += ps[i]; den[b] = dsum; }
}

// tpart[sc][b,h] = sum_{s in 64-chunk sc} sigma[b,s] * KH[b*512+s, h]
__global__ __launch_bounds__(256) void t_reduce(const unsigned short* __restrict__ KH,
                                                const float* __restrict__ sig,
                                                float* __restrict__ tpart) {
  int b = blockIdx.x, hb = blockIdx.y, sc = blockIdx.z;   // (32,4,8)
  int h = hb * 256 + threadIdx.x;
  __shared__ float sl[64];
  if (threadIdx.x < 64) sl[threadIdx.x] = sig[b * 512 + sc * 64 + threadIdx.x];
  __syncthreads();
  float acc = 0.f;
  const unsigned short* base = KH + ((long)b * 512 + sc * 64) * 1024 + h;
#pragma unroll 8
  for (int s = 0; s < 64; ++s) acc += sl[s] * bf2f(base[(long)s * 1024]);
  tpart[sc * 32768 + b * 1024 + h] = acc;
}

// agg[b,o] += (t[b,:] . W2k[:,o] + b2k[o]*den) / den   (t = sum of tpart chunks)
__global__ __launch_bounds__(256) void small_gemm(const float* __restrict__ tpart,
                                                  const float* __restrict__ kw2k,
                                                  const float* __restrict__ kb2k,
                                                  const float* __restrict__ den,
                                                  float* __restrict__ aggsum) {
  int b = blockIdx.x, ob = blockIdx.y, hc = blockIdx.z;   // (32,4,4)
  int o = ob * 256 + threadIdx.x;
  __shared__ float tl[256];
  float tv = 0.f;
#pragma unroll
  for (int sc = 0; sc < 8; ++sc) tv += tpart[sc * 32768 + b * 1024 + hc * 256 + threadIdx.x];
  tl[threadIdx.x] = tv;
  __syncthreads();
  float acc = 0.f;
#pragma unroll 4
  for (int h = 0; h < 256; ++h) acc += tl[h] * kw2k[(long)(hc * 256 + h) * 1025 + o];
  float dn = den[b];
  if (hc == 0) acc += kb2k[o] * dn;
  atomicAdd(&aggsum[b * 1024 + o], acc / dn);
}

// new = dbl*(1-RATE) + (agg/K)*RATE ; split into new_l / new_r
__global__ void final_out(const float* __restrict__ dblf, const float* __restrict__ agg,
                          float* __restrict__ out) {
  long gid = (long)blockIdx.x * 256 + threadIdx.x;
  long e = gid * 4;
  long r = e >> 10; int c = (int)(e & 1023);
  int b = (int)(r >> 9);
  float4 d = *(const float4*)(dblf + e);
  float4 a = *(const float4*)(agg + b * 1024 + c);
  float4 o;
  o.x = d.x * 0.995f + a.x * 0.0005f;
  o.y = d.y * 0.995f + a.y * 0.0005f;
  o.z = d.z * 0.995f + a.z * 0.0005f;
  o.w = d.w * 0.995f + a.w * 0.0005f;
  float* dst = (c < 512) ? (out + 524288 + r * 512 + c)
                         : (out + 524288 + 8388608 + r * 512 + (c - 512));
  *(float4*)dst = o;
}

// ---------------- launch ----------------
extern "C" void kernel_launch(void* const* d_in, const int* in_sizes, int n_in,
                              void* d_out, int out_size, void* d_ws, size_t ws_size,
                              hipStream_t stream) {
  const float* el  = (const float*)d_in[0];
  const float* er  = (const float*)d_in[1];
  const float* w1  = (const float*)d_in[2];
  const float* b1  = (const float*)d_in[3];
  const float* w2  = (const float*)d_in[4];
  const float* b2  = (const float*)d_in[5];
  const float* kw1 = (const float*)d_in[6];
  const float* kb1 = (const float*)d_in[7];
  const float* kw2 = (const float*)d_in[8];
  const float* kb2 = (const float*)d_in[9];
  float* out = (float*)d_out;
  char* ws = (char*)d_ws;

  unsigned short* Xb   = (unsigned short*)(ws + OFF_XB);
  unsigned short* W1t  = (unsigned short*)(ws + OFF_W1T);
  unsigned short* Hb   = (unsigned short*)(ws + OFF_HB);
  unsigned short* W2t  = (unsigned short*)(ws + OFF_W2T);
  float*          OUTf = (float*)(ws + OFF_OUT);
  unsigned short* dblb = (unsigned short*)(ws + OFF_XB);   // reuse Xb
  float*          dblf = (float*)(ws + OFF_HB);            // reuse Hb
  unsigned short* KW1t = (unsigned short*)(ws + OFF_KW1T); // reuse OUT region
  unsigned short* KHb  = (unsigned short*)(ws + OFF_KH);
  float* wpart = (float*)(ws + OFF_WPART);
  float* sig   = (float*)(ws + OFF_SIG);
  float* den   = (float*)(ws + OFF_DEN);
  float* tpart = (float*)(ws + OFF_TPART);
  float* agg   = (float*)(ws + OFF_AGG);
  float* vbuf  = (float*)(ws + OFF_VBUF);

  convert_X<<<16384, 256, 0, stream>>>(el, er, Xb);
  transpose_cvt<<<dim3(64, 32, 1), dim3(32, 8), 0, stream>>>(w1, W1t, 1024, 2048);
  transpose_cvt<<<dim3(65, 64, 1), dim3(32, 8), 0, stream>>>(w2, W2t, 2048, 2080);

  // H = relu(X @ W1 + b1)
  gemm128<1, 1, 0><<<dim3(128, 16, 1), 256, 0, stream>>>(
      Xb, W1t, b1, Hb, nullptr, nullptr, nullptr, 1024, 2048, 2048);
  // OUT = H @ W2 + b2
  gemm128<0, 0, 0><<<dim3(128, 17, 1), 256, 0, stream>>>(
      Hb, W2t, b2, nullptr, OUTf, nullptr, nullptr, 2048, 2080, 2080);

  postproc<<<16384, 256, 0, stream>>>(OUTf, el, er, out, dblf, dblb);

  transpose_cvt<<<dim3(32, 32, 10), dim3(32, 8), 0, stream>>>(kw1, KW1t, 1024, 1024);
  extract_v<<<40, 256, 0, stream>>>(kw2, vbuf);
  hipMemsetAsync(agg, 0, 32 * 1024 * 4, stream);

  for (int k = 0; k < 10; ++k) {
    const float* kw2k = kw2 + (long)k * 1024 * 1025;
    const float* kb2k = kb2 + (long)k * 1025;
    // KH = relu(dbl @ ker_w1[k] + kb1[k]) with fused GEMV partials vs vbuf[k]
    gemm128<1, 1, 1><<<dim3(128, 8, 1), 256, 0, stream>>>(
        dblb, KW1t + (long)k * 1024 * 1024, kb1 + k * 1024, KHb, nullptr,
        vbuf + k * 1024, wpart, 1024, 1024, 1024);
    sigma_den<<<32, 512, 0, stream>>>(wpart, kb2k, sig, den);
    t_reduce<<<dim3(32, 4, 8), 256, 0, stream>>>(KHb, sig, tpart);
    small_gemm<<<dim3(32, 4, 4), 256, 0, stream>>>(tpart, kw2k, kb2k, den, agg);
  }

  final_out<<<16384, 256, 0, stream>>>(dblf, agg, out);
}

// Round 3
// 1414.614 us; speedup vs baseline: 1.1473x; 1.1473x over previous
//
#include <hip/hip_runtime.h>
#include <math.h>

// ---------------------------------------------------------------------------
// MemoryEdgeDecoder: B=32,S=512,E=512 -> N=16384 rows, IN=1024, HID=2048,
// OUT=2080 (=32 decoded + 1024 dbl + 1024 ratio), K=10, RATE=0.005.
//
// R2: all GEMMs ported from m97-style 128^2/2-barrier (585 TF, MfmaUtil 27%,
// 1.8e7 bank conflicts) to a 256^2 / BK=32 / 4-LDS-buffer counted-vmcnt
// schedule (T2 swizzle + T3/T4 counted pipeline + T5 setprio + T1 XCD swz).
// Race-freedom: one s_barrier per K-tile; stage(t+3) writes buf[(t+3)&3] whose
// readers (tile t-1) all passed the end-of-(t-1) barrier; vmcnt(8) at end of
// tile t retires in-order => tile t+1's 4 loads complete. Never vmcnt(0) in
// steady state.
// ---------------------------------------------------------------------------

typedef __bf16 bf16x8 __attribute__((ext_vector_type(8)));
typedef float  f32x4  __attribute__((ext_vector_type(4)));

__device__ __forceinline__ float bf2f(unsigned short u) {
  unsigned int x = ((unsigned int)u) << 16;
  return __builtin_bit_cast(float, x);
}
__device__ __forceinline__ unsigned short f2bf(float f) {
  unsigned int x = __builtin_bit_cast(unsigned int, f);
  x += 0x7fffu + ((x >> 16) & 1u);   // RNE
  return (unsigned short)(x >> 16);
}
__device__ __forceinline__ void gload_lds16(const void* g, void* l) {
  __builtin_amdgcn_global_load_lds(
      (const __attribute__((address_space(1))) unsigned int*)g,
      (__attribute__((address_space(3))) unsigned int*)l, 16, 0, 0);
}
#define WAITV(n) asm volatile("s_waitcnt vmcnt(" #n ")" ::: "memory")
#define MEMFENCE() asm volatile("" ::: "memory")

// ---------------- ws layout (bytes) ----------------
#define OFF_XB    0ull                           // 33,554,432  (reused as dblb)
#define OFF_W1T   (OFF_XB  + 33554432ull)        //  4,194,304
#define OFF_HB    (OFF_W1T + 4194304ull)         // 67,108,864  (reused as dblf)
#define OFF_W2T   (OFF_HB  + 67108864ull)        //  8,912,896  (2176 rows x 2048)
#define OFF_OUT   (OFF_W2T + 8912896ull)         // 136,314,880
// carved out of OUT region after postproc consumed it:
#define OFF_KW1T  OFF_OUT                         // 20,971,520
#define OFF_KH    (OFF_KW1T + 20971520ull)        // 33,554,432
#define OFF_WPART (OFF_KH   + 33554432ull)        //  1,048,576  (16 x 16384 f32)
#define OFF_SIG   (OFF_WPART+ 1048576ull)         //     65,536
#define OFF_DEN   (OFF_SIG  + 65536ull)           //      1,024
#define OFF_TPART (OFF_DEN  + 1024ull)            //  1,048,576  (8 x 32768 f32)
#define OFF_AGG   (OFF_TPART+ 1048576ull)         //    131,072
#define OFF_VBUF  (OFF_AGG  + 131072ull)          //     40,960

// ---------------- small kernels (unchanged from passing R1) ----------------

__global__ void convert_X(const float* __restrict__ el, const float* __restrict__ er,
                          unsigned short* __restrict__ Xb) {
  long gid = (long)blockIdx.x * blockDim.x + threadIdx.x;
  long e = gid * 4;
  long r = e >> 10; int c = (int)(e & 1023);
  const float* s = (c < 512) ? (el + r * 512 + c) : (er + r * 512 + (c - 512));
  float4 v = *(const float4*)s;
  ushort4 o; o.x = f2bf(v.x); o.y = f2bf(v.y); o.z = f2bf(v.z); o.w = f2bf(v.w);
  *(ushort4*)(Xb + e) = o;
}

__global__ void transpose_cvt(const float* __restrict__ src, unsigned short* __restrict__ dst,
                              int R, int C) {
  __shared__ float tile[32][33];
  long zoff = (long)blockIdx.z * R * C;
  src += zoff; dst += zoff;
  int tx = threadIdx.x, ty = threadIdx.y;           // (32, 8)
  long r0 = (long)blockIdx.y * 32, c0 = (long)blockIdx.x * 32;
#pragma unroll
  for (int j = 0; j < 32; j += 8)
    tile[ty + j][tx] = src[(r0 + ty + j) * C + c0 + tx];
  __syncthreads();
#pragma unroll
  for (int j = 0; j < 32; j += 8)
    dst[(c0 + ty + j) * R + r0 + tx] = f2bf(tile[tx][ty + j]);
}

// ---------------- 256^2 counted-vmcnt GEMM ----------------
// A: M x K bf16 (lda=K), Bt: N x K bf16 (ldb=K, rows clamped to nbt-1 on stage).
// C = act(A@B + bias); WB=1 -> bf16 out else f32. Cols >= Nvalid masked.
// GV=1: also emit per-64-col GEMV partials gout[(col64)*16384 + row].
// Grid = (M/256)*(N/256), must be %8==0. 512 threads = 8 waves (2M x 4N).
// LDS: 4 buffers x (A[256][32] + B[256][32]) bf16, chunk-swizzled:
//   LDS[row][cc] (16B chunks cc=0..3) holds global k-chunk cc^(row&3).
template <int RELU, int WB, int GV>
__global__ __launch_bounds__(512, 2) void gemm256(
    const unsigned short* __restrict__ A, const unsigned short* __restrict__ Bt,
    const float* __restrict__ bias, unsigned short* __restrict__ Cb,
    float* __restrict__ Cf, const float* __restrict__ gvec,
    float* __restrict__ gout, int K, int NB, int Nvalid, int ldc, int nbt) {
  __shared__ unsigned short lds[65536];   // 128 KiB
  const int tid = threadIdx.x;
  const int wv = tid >> 6, ln = tid & 63;
  const int nwg = gridDim.x;
  const int swz = (blockIdx.x & 7) * (nwg >> 3) + (blockIdx.x >> 3);  // bijective, nwg%8==0
  const long m0 = (long)(swz / NB) * 256;
  const long n0 = (long)(swz % NB) * 256;
  const int wr = wv >> 2, wc = wv & 3;    // wave -> (2 x 4) output grid
  const int lr = ln >> 4, lc = ln & 15;
  const int nt = K >> 5;                  // K-tiles of 32

  f32x4 acc[8][4] = {};

  // staging: 4 gload_lds16 per thread per tile (2 A + 2 B halves)
  auto stage = [&](int t) {
    const int buf = t & 3;
    const long kt = (long)t << 5;
    unsigned short* la = &lds[buf * 16384];
    unsigned short* lb = la + 8192;
#pragma unroll
    for (int i = 0; i < 2; ++i) {
      int c = tid + i * 512;              // chunk 0..1023
      int row = c >> 2, cc = c & 3;
      int sc = cc ^ (row & 3);            // pre-swizzled global source chunk
      gload_lds16(A + (m0 + row) * K + kt + sc * 8, la + c * 8);
    }
#pragma unroll
    for (int i = 0; i < 2; ++i) {
      int c = tid + i * 512;
      int row = c >> 2, cc = c & 3;
      int sc = cc ^ (row & 3);
      long brow = n0 + row;
      if (brow >= nbt) brow = nbt - 1;    // clamp (GEMM2 tail tile); masked at write
      gload_lds16(Bt + brow * K + kt + sc * 8, lb + c * 8);
    }
  };

  auto compute = [&](int t) {
    const int buf = t & 3;
    const unsigned short* la = &lds[buf * 16384];
    const unsigned short* lb = la + 8192;
    bf16x8 bfr[4];
#pragma unroll
    for (int ni = 0; ni < 4; ++ni) {
      int row = wc * 64 + ni * 16 + lc;
      bfr[ni] = *(const bf16x8*)&lb[row * 32 + ((lr ^ (row & 3)) * 8)];
    }
    __builtin_amdgcn_s_setprio(1);
#pragma unroll
    for (int mi = 0; mi < 8; ++mi) {
      int row = wr * 128 + mi * 16 + lc;
      bf16x8 af = *(const bf16x8*)&la[row * 32 + ((lr ^ (row & 3)) * 8)];
#pragma unroll
      for (int ni = 0; ni < 4; ++ni)
        acc[mi][ni] = __builtin_amdgcn_mfma_f32_16x16x32_bf16(af, bfr[ni], acc[mi][ni], 0, 0, 0);
    }
    __builtin_amdgcn_s_setprio(0);
  };

  // prologue: 3 tiles in flight, wait for tile 0 (8 = tiles 1,2 outstanding)
  stage(0); stage(1); stage(2);
  WAITV(8);
  __builtin_amdgcn_s_barrier();
  MEMFENCE();

  for (int t = 0; t < nt; ++t) {
    if (t + 3 < nt) stage(t + 3);
    compute(t);
    // end-of-tile: guarantee tile t+1 resident; allow tiles t+2,t+3 in flight
    if (t + 3 < nt)      WAITV(8);
    else if (t + 2 < nt) WAITV(4);
    else                 WAITV(0);
    __builtin_amdgcn_s_barrier();
    MEMFENCE();
  }

  // epilogue
  long colv[4]; bool okv[4]; float bv[4], gvv[4];
#pragma unroll
  for (int ni = 0; ni < 4; ++ni) {
    colv[ni] = n0 + wc * 64 + ni * 16 + lc;
    okv[ni] = colv[ni] < Nvalid;
    bv[ni] = okv[ni] ? bias[colv[ni]] : 0.f;
    gvv[ni] = GV ? gvec[colv[ni]] : 0.f;
  }
#pragma unroll
  for (int mi = 0; mi < 8; ++mi) {
#pragma unroll
    for (int j = 0; j < 4; ++j) {
      long row = m0 + wr * 128 + mi * 16 + lr * 4 + j;
      float p = 0.f;
#pragma unroll
      for (int ni = 0; ni < 4; ++ni) {
        float v = acc[mi][ni][j] + bv[ni];
        if (RELU) v = fmaxf(v, 0.f);
        if (okv[ni]) {
          if (WB) Cb[row * ldc + colv[ni]] = f2bf(v);
          else    Cf[row * ldc + colv[ni]] = v;
        }
        if (GV) p += v * gvv[ni];
      }
      if (GV) {
#pragma unroll
        for (int off = 1; off < 16; off <<= 1) p += __shfl_xor(p, off);
        if (lc == 0) gout[((n0 >> 6) + wc) * 16384 + row] = p;
      }
    }
  }
}

// decoded -> d_out; dbl = out*g + prev*(1-g) in f32 + bf16
__global__ void postproc(const float* __restrict__ OUT, const float* __restrict__ el,
                         const float* __restrict__ er, float* __restrict__ dec,
                         float* __restrict__ dblf, unsigned short* __restrict__ dblb) {
  long r = blockIdx.x;
  int t = threadIdx.x;
  const float* orow = OUT + r * 2080;
  if (t < 8) {
    float4 v = *(const float4*)(orow + t * 4);
    *(float4*)(dec + r * 32 + t * 4) = v;
  }
  int c = t * 4;
  float4 d  = *(const float4*)(orow + 32 + c);
  float4 rt = *(const float4*)(orow + 1056 + c);
  const float* pp = (c < 512) ? (el + r * 512 + c) : (er + r * 512 + (c - 512));
  float4 p = *(const float4*)pp;
  float4 o; float g;
  g = 1.f / (1.f + expf(-rt.x)); o.x = d.x * g + p.x * (1.f - g);
  g = 1.f / (1.f + expf(-rt.y)); o.y = d.y * g + p.y * (1.f - g);
  g = 1.f / (1.f + expf(-rt.z)); o.z = d.z * g + p.z * (1.f - g);
  g = 1.f / (1.f + expf(-rt.w)); o.w = d.w * g + p.w * (1.f - g);
  *(float4*)(dblf + r * 1024 + c) = o;
  ushort4 ob; ob.x = f2bf(o.x); ob.y = f2bf(o.y); ob.z = f2bf(o.z); ob.w = f2bf(o.w);
  *(ushort4*)(dblb + r * 1024 + c) = ob;
}

__global__ void extract_v(const float* __restrict__ kw2, float* __restrict__ vbuf) {
  int i = blockIdx.x * 256 + threadIdx.x;  // 0..10239
  int k = i >> 10, h = i & 1023;
  vbuf[i] = kw2[(long)k * 1024 * 1025 + (long)h * 1025 + 1024];
}

// sigma = sigmoid(sum_c wpart[c][row] + last_bias); den[b] = sum_s sigma
__global__ __launch_bounds__(512) void sigma_den(const float* __restrict__ wpart,
                                                 const float* __restrict__ kb2k,
                                                 float* __restrict__ sig, float* __restrict__ den) {
  int b = blockIdx.x, t = threadIdx.x;
  int row = b * 512 + t;
  float x = kb2k[1024];
#pragma unroll
  for (int c = 0; c < 16; ++c) x += wpart[c * 16384 + row];
  float s = 1.f / (1.f + expf(-x));
  sig[row] = s;
  float v = s;
#pragma unroll
  for (int off = 32; off >= 1; off >>= 1) v += __shfl_down(v, off);
  __shared__ float ps[8];
  if ((t & 63) == 0) ps[t >> 6] = v;
  __syncthreads();
  if (t == 0) { float dsum = 0.f; for (int i = 0; i < 8; ++i) dsum += ps[i]; den[b] = dsum; }
}

// tpart[sc][b,h] = sum_{s in 64-chunk sc} sigma[b,s] * KH[b*512+s, h]
__global__ __launch_bounds__(256) void t_reduce(const unsigned short* __restrict__ KH,
                                                const float* __restrict__ sig,
                                                float* __restrict__ tpart) {
  int b = blockIdx.x, hb = blockIdx.y, sc = blockIdx.z;   // (32,4,8)
  int h = hb * 256 + threadIdx.x;
  __shared__ float sl[64];
  if (threadIdx.x < 64) sl[threadIdx.x] = sig[b * 512 + sc * 64 + threadIdx.x];
  __syncthreads();
  float acc = 0.f;
  const unsigned short* base = KH + ((long)b * 512 + sc * 64) * 1024 + h;
#pragma unroll 8
  for (int s = 0; s < 64; ++s) acc += sl[s] * bf2f(base[(long)s * 1024]);
  tpart[sc * 32768 + b * 1024 + h] = acc;
}

// agg[b,o] += (t[b,:] . W2k[:,o] + b2k[o]*den) / den   (t = sum of tpart chunks)
__global__ __launch_bounds__(256) void small_gemm(const float* __restrict__ tpart,
                                                  const float* __restrict__ kw2k,
                                                  const float* __restrict__ kb2k,
                                                  const float* __restrict__ den,
                                                  float* __restrict__ aggsum) {
  int b = blockIdx.x, ob = blockIdx.y, hc = blockIdx.z;   // (32,4,4)
  int o = ob * 256 + threadIdx.x;
  __shared__ float tl[256];
  float tv = 0.f;
#pragma unroll
  for (int sc = 0; sc < 8; ++sc) tv += tpart[sc * 32768 + b * 1024 + hc * 256 + threadIdx.x];
  tl[threadIdx.x] = tv;
  __syncthreads();
  float acc = 0.f;
#pragma unroll 4
  for (int h = 0; h < 256; ++h) acc += tl[h] * kw2k[(long)(hc * 256 + h) * 1025 + o];
  float dn = den[b];
  if (hc == 0) acc += kb2k[o] * dn;
  atomicAdd(&aggsum[b * 1024 + o], acc / dn);
}

// new = dbl*(1-RATE) + (agg/K)*RATE ; split into new_l / new_r
__global__ void final_out(const float* __restrict__ dblf, const float* __restrict__ agg,
                          float* __restrict__ out) {
  long gid = (long)blockIdx.x * 256 + threadIdx.x;
  long e = gid * 4;
  long r = e >> 10; int c = (int)(e & 1023);
  int b = (int)(r >> 9);
  float4 d = *(const float4*)(dblf + e);
  float4 a = *(const float4*)(agg + b * 1024 + c);
  float4 o;
  o.x = d.x * 0.995f + a.x * 0.0005f;
  o.y = d.y * 0.995f + a.y * 0.0005f;
  o.z = d.z * 0.995f + a.z * 0.0005f;
  o.w = d.w * 0.995f + a.w * 0.0005f;
  float* dst = (c < 512) ? (out + 524288 + r * 512 + c)
                         : (out + 524288 + 8388608 + r * 512 + (c - 512));
  *(float4*)dst = o;
}

// ---------------- launch ----------------
extern "C" void kernel_launch(void* const* d_in, const int* in_sizes, int n_in,
                              void* d_out, int out_size, void* d_ws, size_t ws_size,
                              hipStream_t stream) {
  const float* el  = (const float*)d_in[0];
  const float* er  = (const float*)d_in[1];
  const float* w1  = (const float*)d_in[2];
  const float* b1  = (const float*)d_in[3];
  const float* w2  = (const float*)d_in[4];
  const float* b2  = (const float*)d_in[5];
  const float* kw1 = (const float*)d_in[6];
  const float* kb1 = (const float*)d_in[7];
  const float* kw2 = (const float*)d_in[8];
  const float* kb2 = (const float*)d_in[9];
  float* out = (float*)d_out;
  char* ws = (char*)d_ws;

  unsigned short* Xb   = (unsigned short*)(ws + OFF_XB);
  unsigned short* W1t  = (unsigned short*)(ws + OFF_W1T);
  unsigned short* Hb   = (unsigned short*)(ws + OFF_HB);
  unsigned short* W2t  = (unsigned short*)(ws + OFF_W2T);
  float*          OUTf = (float*)(ws + OFF_OUT);
  unsigned short* dblb = (unsigned short*)(ws + OFF_XB);   // reuse Xb
  float*          dblf = (float*)(ws + OFF_HB);            // reuse Hb
  unsigned short* KW1t = (unsigned short*)(ws + OFF_KW1T); // reuse OUT region
  unsigned short* KHb  = (unsigned short*)(ws + OFF_KH);
  float* wpart = (float*)(ws + OFF_WPART);
  float* sig   = (float*)(ws + OFF_SIG);
  float* den   = (float*)(ws + OFF_DEN);
  float* tpart = (float*)(ws + OFF_TPART);
  float* agg   = (float*)(ws + OFF_AGG);
  float* vbuf  = (float*)(ws + OFF_VBUF);

  convert_X<<<16384, 256, 0, stream>>>(el, er, Xb);
  transpose_cvt<<<dim3(64, 32, 1), dim3(32, 8), 0, stream>>>(w1, W1t, 1024, 2048);
  transpose_cvt<<<dim3(65, 64, 1), dim3(32, 8), 0, stream>>>(w2, W2t, 2048, 2080);

  // H = relu(X @ W1 + b1): M=16384, N=2048, K=1024 -> grid 64*8=512
  gemm256<1, 1, 0><<<512, 512, 0, stream>>>(
      Xb, W1t, b1, Hb, nullptr, nullptr, nullptr, 1024, 8, 2048, 2048, 2048);
  // OUT = H @ W2 + b2: M=16384, N=2080 (9 col-tiles, masked), K=2048 -> 576
  gemm256<0, 0, 0><<<576, 512, 0, stream>>>(
      Hb, W2t, b2, nullptr, OUTf, nullptr, nullptr, 2048, 9, 2080, 2080, 2176);

  postproc<<<16384, 256, 0, stream>>>(OUTf, el, er, out, dblf, dblb);

  transpose_cvt<<<dim3(32, 32, 10), dim3(32, 8), 0, stream>>>(kw1, KW1t, 1024, 1024);
  extract_v<<<40, 256, 0, stream>>>(kw2, vbuf);
  hipMemsetAsync(agg, 0, 32 * 1024 * 4, stream);

  for (int k = 0; k < 10; ++k) {
    const float* kw2k = kw2 + (long)k * 1024 * 1025;
    const float* kb2k = kb2 + (long)k * 1025;
    // KH = relu(dbl @ ker_w1[k] + kb1[k]) with fused GEMV partials vs vbuf[k]
    gemm256<1, 1, 1><<<256, 512, 0, stream>>>(
        dblb, KW1t + (long)k * 1024 * 1024, kb1 + k * 1024, KHb, nullptr,
        vbuf + k * 1024, wpart, 1024, 4, 1024, 1024, 1024);
    sigma_den<<<32, 512, 0, stream>>>(wpart, kb2k, sig, den);
    t_reduce<<<dim3(32, 4, 8), 256, 0, stream>>>(KHb, sig, tpart);
    small_gemm<<<dim3(32, 4, 4), 256, 0, stream>>>(tpart, kw2k, kb2k, den, agg);
  }

  final_out<<<16384, 256, 0, stream>>>(dblf, agg, out);
}

// Round 4
// 1398.920 us; speedup vs baseline: 1.1601x; 1.0112x over previous
//
#include <hip/hip_runtime.h>
#include <math.h>

// ---------------------------------------------------------------------------
// MemoryEdgeDecoder: B=32,S=512,E=512 -> N=16384 rows, IN=1024, HID=2048,
// OUT=2080 (=32 decoded + 1024 dbl + 1024 ratio), K=10, RATE=0.005.
//
// R3: on the PASSING R2 256^2/BK=32/4-buf counted-vmcnt skeleton:
//  (a) swizzle FIX: chunk ^= (row>>1)&3 (was row&3, which correlated chunk
//      parity with row parity -> 4-way bank conflict, 1.4e7 measured).
//      New XOR spreads each 16-lane fragment read across all 8 16B-quads,
//      2 lanes each (2-way = free, m136).
//  (b) 2-phase compute per K-tile with mid-tile s_barrier + setprio around
//      each 16-MFMA cluster (wave role-split so setprio has something to
//      arbitrate; T5 requires phase structure, m218b).
// Sync invariants unchanged from R2 (verified passing): stage(t+3) targets
// buf (t+3)&3 whose readers finished at end-of-(t-1) barrier; vmcnt(8) at
// tile end guarantees t+1 resident (in-order retirement); never vmcnt(0)
// in steady state.
// ---------------------------------------------------------------------------

typedef __bf16 bf16x8 __attribute__((ext_vector_type(8)));
typedef float  f32x4  __attribute__((ext_vector_type(4)));

__device__ __forceinline__ float bf2f(unsigned short u) {
  unsigned int x = ((unsigned int)u) << 16;
  return __builtin_bit_cast(float, x);
}
__device__ __forceinline__ unsigned short f2bf(float f) {
  unsigned int x = __builtin_bit_cast(unsigned int, f);
  x += 0x7fffu + ((x >> 16) & 1u);   // RNE
  return (unsigned short)(x >> 16);
}
__device__ __forceinline__ void gload_lds16(const void* g, void* l) {
  __builtin_amdgcn_global_load_lds(
      (const __attribute__((address_space(1))) unsigned int*)g,
      (__attribute__((address_space(3))) unsigned int*)l, 16, 0, 0);
}
#define WAITV(n) asm volatile("s_waitcnt vmcnt(" #n ")" ::: "memory")
#define MEMFENCE() asm volatile("" ::: "memory")

// ---------------- ws layout (bytes) ----------------
#define OFF_XB    0ull                           // 33,554,432  (reused as dblb)
#define OFF_W1T   (OFF_XB  + 33554432ull)        //  4,194,304
#define OFF_HB    (OFF_W1T + 4194304ull)         // 67,108,864  (reused as dblf)
#define OFF_W2T   (OFF_HB  + 67108864ull)        //  8,912,896  (2176 rows x 2048)
#define OFF_OUT   (OFF_W2T + 8912896ull)         // 136,314,880
// carved out of OUT region after postproc consumed it:
#define OFF_KW1T  OFF_OUT                         // 20,971,520
#define OFF_KH    (OFF_KW1T + 20971520ull)        // 33,554,432
#define OFF_WPART (OFF_KH   + 33554432ull)        //  1,048,576  (16 x 16384 f32)
#define OFF_SIG   (OFF_WPART+ 1048576ull)         //     65,536
#define OFF_DEN   (OFF_SIG  + 65536ull)           //      1,024
#define OFF_TPART (OFF_DEN  + 1024ull)            //  1,048,576  (8 x 32768 f32)
#define OFF_AGG   (OFF_TPART+ 1048576ull)         //    131,072
#define OFF_VBUF  (OFF_AGG  + 131072ull)          //     40,960

// ---------------- small kernels (unchanged, passing) ----------------

__global__ void convert_X(const float* __restrict__ el, const float* __restrict__ er,
                          unsigned short* __restrict__ Xb) {
  long gid = (long)blockIdx.x * blockDim.x + threadIdx.x;
  long e = gid * 4;
  long r = e >> 10; int c = (int)(e & 1023);
  const float* s = (c < 512) ? (el + r * 512 + c) : (er + r * 512 + (c - 512));
  float4 v = *(const float4*)s;
  ushort4 o; o.x = f2bf(v.x); o.y = f2bf(v.y); o.z = f2bf(v.z); o.w = f2bf(v.w);
  *(ushort4*)(Xb + e) = o;
}

__global__ void transpose_cvt(const float* __restrict__ src, unsigned short* __restrict__ dst,
                              int R, int C) {
  __shared__ float tile[32][33];
  long zoff = (long)blockIdx.z * R * C;
  src += zoff; dst += zoff;
  int tx = threadIdx.x, ty = threadIdx.y;           // (32, 8)
  long r0 = (long)blockIdx.y * 32, c0 = (long)blockIdx.x * 32;
#pragma unroll
  for (int j = 0; j < 32; j += 8)
    tile[ty + j][tx] = src[(r0 + ty + j) * C + c0 + tx];
  __syncthreads();
#pragma unroll
  for (int j = 0; j < 32; j += 8)
    dst[(c0 + ty + j) * R + r0 + tx] = f2bf(tile[tx][ty + j]);
}

// ---------------- 256^2 counted-vmcnt GEMM ----------------
// A: M x K bf16 (lda=K), Bt: N x K bf16 (ldb=K, rows clamped to nbt-1 on stage).
// C = act(A@B + bias); WB=1 -> bf16 out else f32. Cols >= Nvalid masked.
// GV=1: also emit per-64-col GEMV partials gout[(col64)*16384 + row].
// Grid = (M/256)*(N/256), must be %8==0. 512 threads = 8 waves (2M x 4N).
// LDS: 4 buffers x (A[256][32] + B[256][32]) bf16; chunk-swizzle:
//   LDS chunk cc of row r holds global 16B-chunk cc ^ ((r>>1)&3).
template <int RELU, int WB, int GV>
__global__ __launch_bounds__(512, 2) void gemm256(
    const unsigned short* __restrict__ A, const unsigned short* __restrict__ Bt,
    const float* __restrict__ bias, unsigned short* __restrict__ Cb,
    float* __restrict__ Cf, const float* __restrict__ gvec,
    float* __restrict__ gout, int K, int NB, int Nvalid, int ldc, int nbt) {
  __shared__ unsigned short lds[65536];   // 128 KiB
  const int tid = threadIdx.x;
  const int wv = tid >> 6, ln = tid & 63;
  const int nwg = gridDim.x;
  const int swz = (blockIdx.x & 7) * (nwg >> 3) + (blockIdx.x >> 3);  // bijective, nwg%8==0
  const long m0 = (long)(swz / NB) * 256;
  const long n0 = (long)(swz % NB) * 256;
  const int wr = wv >> 2, wc = wv & 3;    // wave -> (2 x 4) output grid
  const int lr = ln >> 4, lc = ln & 15;
  const int nt = K >> 5;                  // K-tiles of 32

  f32x4 acc[8][4] = {};

  // staging: 4 gload_lds16 per thread per tile (2 A + 2 B halves)
  auto stage = [&](int t) {
    const int buf = t & 3;
    const long kt = (long)t << 5;
    unsigned short* la = &lds[buf * 16384];
    unsigned short* lb = la + 8192;
#pragma unroll
    for (int i = 0; i < 2; ++i) {
      int c = tid + i * 512;              // chunk 0..1023
      int row = c >> 2, cc = c & 3;
      int sc = cc ^ ((row >> 1) & 3);     // pre-swizzled global source chunk
      gload_lds16(A + (m0 + row) * K + kt + sc * 8, la + c * 8);
    }
#pragma unroll
    for (int i = 0; i < 2; ++i) {
      int c = tid + i * 512;
      int row = c >> 2, cc = c & 3;
      int sc = cc ^ ((row >> 1) & 3);
      long brow = n0 + row;
      if (brow >= nbt) brow = nbt - 1;    // clamp (GEMM2 tail tile); masked at write
      gload_lds16(Bt + brow * K + kt + sc * 8, lb + c * 8);
    }
  };

  // 2-phase compute: phase0 = B-frags + A-frags mi0-3 + 16 MFMA;
  // mid-tile barrier; phase1 = A-frags mi4-7 + 16 MFMA.
  auto compute = [&](int t) {
    const int buf = t & 3;
    const unsigned short* la = &lds[buf * 16384];
    const unsigned short* lb = la + 8192;
    bf16x8 bfr[4];
#pragma unroll
    for (int ni = 0; ni < 4; ++ni) {
      int row = wc * 64 + ni * 16 + lc;
      bfr[ni] = *(const bf16x8*)&lb[row * 32 + ((lr ^ ((row >> 1) & 3)) * 8)];
    }
    bf16x8 af[4];
#pragma unroll
    for (int mi = 0; mi < 4; ++mi) {
      int row = wr * 128 + mi * 16 + lc;
      af[mi] = *(const bf16x8*)&la[row * 32 + ((lr ^ ((row >> 1) & 3)) * 8)];
    }
    __builtin_amdgcn_s_setprio(1);
#pragma unroll
    for (int mi = 0; mi < 4; ++mi)
#pragma unroll
      for (int ni = 0; ni < 4; ++ni)
        acc[mi][ni] = __builtin_amdgcn_mfma_f32_16x16x32_bf16(af[mi], bfr[ni], acc[mi][ni], 0, 0, 0);
    __builtin_amdgcn_s_setprio(0);
    __builtin_amdgcn_s_barrier();         // mid-tile pacing (all 512 threads)
    bf16x8 a2[4];
#pragma unroll
    for (int mi = 0; mi < 4; ++mi) {
      int row = wr * 128 + (mi + 4) * 16 + lc;
      a2[mi] = *(const bf16x8*)&la[row * 32 + ((lr ^ ((row >> 1) & 3)) * 8)];
    }
    __builtin_amdgcn_s_setprio(1);
#pragma unroll
    for (int mi = 0; mi < 4; ++mi)
#pragma unroll
      for (int ni = 0; ni < 4; ++ni)
        acc[mi + 4][ni] = __builtin_amdgcn_mfma_f32_16x16x32_bf16(a2[mi], bfr[ni], acc[mi + 4][ni], 0, 0, 0);
    __builtin_amdgcn_s_setprio(0);
  };

  // prologue: 3 tiles in flight, wait for tile 0 (8 = tiles 1,2 outstanding)
  stage(0); stage(1); stage(2);
  WAITV(8);
  __builtin_amdgcn_s_barrier();
  MEMFENCE();

  for (int t = 0; t < nt; ++t) {
    if (t + 3 < nt) stage(t + 3);
    compute(t);
    // end-of-tile: guarantee tile t+1 resident; allow tiles t+2,t+3 in flight
    if (t + 3 < nt)      WAITV(8);
    else if (t + 2 < nt) WAITV(4);
    else                 WAITV(0);
    __builtin_amdgcn_s_barrier();
    MEMFENCE();
  }

  // epilogue
  long colv[4]; bool okv[4]; float bv[4], gvv[4];
#pragma unroll
  for (int ni = 0; ni < 4; ++ni) {
    colv[ni] = n0 + wc * 64 + ni * 16 + lc;
    okv[ni] = colv[ni] < Nvalid;
    bv[ni] = okv[ni] ? bias[colv[ni]] : 0.f;
    gvv[ni] = GV ? gvec[colv[ni]] : 0.f;
  }
#pragma unroll
  for (int mi = 0; mi < 8; ++mi) {
#pragma unroll
    for (int j = 0; j < 4; ++j) {
      long row = m0 + wr * 128 + mi * 16 + lr * 4 + j;
      float p = 0.f;
#pragma unroll
      for (int ni = 0; ni < 4; ++ni) {
        float v = acc[mi][ni][j] + bv[ni];
        if (RELU) v = fmaxf(v, 0.f);
        if (okv[ni]) {
          if (WB) Cb[row * ldc + colv[ni]] = f2bf(v);
          else    Cf[row * ldc + colv[ni]] = v;
        }
        if (GV) p += v * gvv[ni];
      }
      if (GV) {
#pragma unroll
        for (int off = 1; off < 16; off <<= 1) p += __shfl_xor(p, off);
        if (lc == 0) gout[((n0 >> 6) + wc) * 16384 + row] = p;
      }
    }
  }
}

// decoded -> d_out; dbl = out*g + prev*(1-g) in f32 + bf16
__global__ void postproc(const float* __restrict__ OUT, const float* __restrict__ el,
                         const float* __restrict__ er, float* __restrict__ dec,
                         float* __restrict__ dblf, unsigned short* __restrict__ dblb) {
  long r = blockIdx.x;
  int t = threadIdx.x;
  const float* orow = OUT + r * 2080;
  if (t < 8) {
    float4 v = *(const float4*)(orow + t * 4);
    *(float4*)(dec + r * 32 + t * 4) = v;
  }
  int c = t * 4;
  float4 d  = *(const float4*)(orow + 32 + c);
  float4 rt = *(const float4*)(orow + 1056 + c);
  const float* pp = (c < 512) ? (el + r * 512 + c) : (er + r * 512 + (c - 512));
  float4 p = *(const float4*)pp;
  float4 o; float g;
  g = 1.f / (1.f + expf(-rt.x)); o.x = d.x * g + p.x * (1.f - g);
  g = 1.f / (1.f + expf(-rt.y)); o.y = d.y * g + p.y * (1.f - g);
  g = 1.f / (1.f + expf(-rt.z)); o.z = d.z * g + p.z * (1.f - g);
  g = 1.f / (1.f + expf(-rt.w)); o.w = d.w * g + p.w * (1.f - g);
  *(float4*)(dblf + r * 1024 + c) = o;
  ushort4 ob; ob.x = f2bf(o.x); ob.y = f2bf(o.y); ob.z = f2bf(o.z); ob.w = f2bf(o.w);
  *(ushort4*)(dblb + r * 1024 + c) = ob;
}

__global__ void extract_v(const float* __restrict__ kw2, float* __restrict__ vbuf) {
  int i = blockIdx.x * 256 + threadIdx.x;  // 0..10239
  int k = i >> 10, h = i & 1023;
  vbuf[i] = kw2[(long)k * 1024 * 1025 + (long)h * 1025 + 1024];
}

// sigma = sigmoid(sum_c wpart[c][row] + last_bias); den[b] = sum_s sigma
__global__ __launch_bounds__(512) void sigma_den(const float* __restrict__ wpart,
                                                 const float* __restrict__ kb2k,
                                                 float* __restrict__ sig, float* __restrict__ den) {
  int b = blockIdx.x, t = threadIdx.x;
  int row = b * 512 + t;
  float x = kb2k[1024];
#pragma unroll
  for (int c = 0; c < 16; ++c) x += wpart[c * 16384 + row];
  float s = 1.f / (1.f + expf(-x));
  sig[row] = s;
  float v = s;
#pragma unroll
  for (int off = 32; off >= 1; off >>= 1) v += __shfl_down(v, off);
  __shared__ float ps[8];
  if ((t & 63) == 0) ps[t >> 6] = v;
  __syncthreads();
  if (t == 0) { float dsum = 0.f; for (int i = 0; i < 8; ++i) dsum += ps[i]; den[b] = dsum; }
}

// tpart[sc][b,h] = sum_{s in 64-chunk sc} sigma[b,s] * KH[b*512+s, h]
__global__ __launch_bounds__(256) void t_reduce(const unsigned short* __restrict__ KH,
                                                const float* __restrict__ sig,
                                                float* __restrict__ tpart) {
  int b = blockIdx.x, hb = blockIdx.y, sc = blockIdx.z;   // (32,4,8)
  int h = hb * 256 + threadIdx.x;
  __shared__ float sl[64];
  if (threadIdx.x < 64) sl[threadIdx.x] = sig[b * 512 + sc * 64 + threadIdx.x];
  __syncthreads();
  float acc = 0.f;
  const unsigned short* base = KH + ((long)b * 512 + sc * 64) * 1024 + h;
#pragma unroll 8
  for (int s = 0; s < 64; ++s) acc += sl[s] * bf2f(base[(long)s * 1024]);
  tpart[sc * 32768 + b * 1024 + h] = acc;
}

// agg[b,o] += (t[b,:] . W2k[:,o] + b2k[o]*den) / den   (t = sum of tpart chunks)
__global__ __launch_bounds__(256) void small_gemm(const float* __restrict__ tpart,
                                                  const float* __restrict__ kw2k,
                                                  const float* __restrict__ kb2k,
                                                  const float* __restrict__ den,
                                                  float* __restrict__ aggsum) {
  int b = blockIdx.x, ob = blockIdx.y, hc = blockIdx.z;   // (32,4,4)
  int o = ob * 256 + threadIdx.x;
  __shared__ float tl[256];
  float tv = 0.f;
#pragma unroll
  for (int sc = 0; sc < 8; ++sc) tv += tpart[sc * 32768 + b * 1024 + hc * 256 + threadIdx.x];
  tl[threadIdx.x] = tv;
  __syncthreads();
  float acc = 0.f;
#pragma unroll 4
  for (int h = 0; h < 256; ++h) acc += tl[h] * kw2k[(long)(hc * 256 + h) * 1025 + o];
  float dn = den[b];
  if (hc == 0) acc += kb2k[o] * dn;
  atomicAdd(&aggsum[b * 1024 + o], acc / dn);
}

// new = dbl*(1-RATE) + (agg/K)*RATE ; split into new_l / new_r
__global__ void final_out(const float* __restrict__ dblf, const float* __restrict__ agg,
                          float* __restrict__ out) {
  long gid = (long)blockIdx.x * 256 + threadIdx.x;
  long e = gid * 4;
  long r = e >> 10; int c = (int)(e & 1023);
  int b = (int)(r >> 9);
  float4 d = *(const float4*)(dblf + e);
  float4 a = *(const float4*)(agg + b * 1024 + c);
  float4 o;
  o.x = d.x * 0.995f + a.x * 0.0005f;
  o.y = d.y * 0.995f + a.y * 0.0005f;
  o.z = d.z * 0.995f + a.z * 0.0005f;
  o.w = d.w * 0.995f + a.w * 0.0005f;
  float* dst = (c < 512) ? (out + 524288 + r * 512 + c)
                         : (out + 524288 + 8388608 + r * 512 + (c - 512));
  *(float4*)dst = o;
}

// ---------------- launch ----------------
extern "C" void kernel_launch(void* const* d_in, const int* in_sizes, int n_in,
                              void* d_out, int out_size, void* d_ws, size_t ws_size,
                              hipStream_t stream) {
  const float* el  = (const float*)d_in[0];
  const float* er  = (const float*)d_in[1];
  const float* w1  = (const float*)d_in[2];
  const float* b1  = (const float*)d_in[3];
  const float* w2  = (const float*)d_in[4];
  const float* b2  = (const float*)d_in[5];
  const float* kw1 = (const float*)d_in[6];
  const float* kb1 = (const float*)d_in[7];
  const float* kw2 = (const float*)d_in[8];
  const float* kb2 = (const float*)d_in[9];
  float* out = (float*)d_out;
  char* ws = (char*)d_ws;

  unsigned short* Xb   = (unsigned short*)(ws + OFF_XB);
  unsigned short* W1t  = (unsigned short*)(ws + OFF_W1T);
  unsigned short* Hb   = (unsigned short*)(ws + OFF_HB);
  unsigned short* W2t  = (unsigned short*)(ws + OFF_W2T);
  float*          OUTf = (float*)(ws + OFF_OUT);
  unsigned short* dblb = (unsigned short*)(ws + OFF_XB);   // reuse Xb
  float*          dblf = (float*)(ws + OFF_HB);            // reuse Hb
  unsigned short* KW1t = (unsigned short*)(ws + OFF_KW1T); // reuse OUT region
  unsigned short* KHb  = (unsigned short*)(ws + OFF_KH);
  float* wpart = (float*)(ws + OFF_WPART);
  float* sig   = (float*)(ws + OFF_SIG);
  float* den   = (float*)(ws + OFF_DEN);
  float* tpart = (float*)(ws + OFF_TPART);
  float* agg   = (float*)(ws + OFF_AGG);
  float* vbuf  = (float*)(ws + OFF_VBUF);

  convert_X<<<16384, 256, 0, stream>>>(el, er, Xb);
  transpose_cvt<<<dim3(64, 32, 1), dim3(32, 8), 0, stream>>>(w1, W1t, 1024, 2048);
  transpose_cvt<<<dim3(65, 64, 1), dim3(32, 8), 0, stream>>>(w2, W2t, 2048, 2080);

  // H = relu(X @ W1 + b1): M=16384, N=2048, K=1024 -> grid 64*8=512
  gemm256<1, 1, 0><<<512, 512, 0, stream>>>(
      Xb, W1t, b1, Hb, nullptr, nullptr, nullptr, 1024, 8, 2048, 2048, 2048);
  // OUT = H @ W2 + b2: M=16384, N=2080 (9 col-tiles, masked), K=2048 -> 576
  gemm256<0, 0, 0><<<576, 512, 0, stream>>>(
      Hb, W2t, b2, nullptr, OUTf, nullptr, nullptr, 2048, 9, 2080, 2080, 2176);

  postproc<<<16384, 256, 0, stream>>>(OUTf, el, er, out, dblf, dblb);

  transpose_cvt<<<dim3(32, 32, 10), dim3(32, 8), 0, stream>>>(kw1, KW1t, 1024, 1024);
  extract_v<<<40, 256, 0, stream>>>(kw2, vbuf);
  hipMemsetAsync(agg, 0, 32 * 1024 * 4, stream);

  for (int k = 0; k < 10; ++k) {
    const float* kw2k = kw2 + (long)k * 1024 * 1025;
    const float* kb2k = kb2 + (long)k * 1025;
    // KH = relu(dbl @ ker_w1[k] + kb1[k]) with fused GEMV partials vs vbuf[k]
    gemm256<1, 1, 1><<<256, 512, 0, stream>>>(
        dblb, KW1t + (long)k * 1024 * 1024, kb1 + k * 1024, KHb, nullptr,
        vbuf + k * 1024, wpart, 1024, 4, 1024, 1024, 1024);
    sigma_den<<<32, 512, 0, stream>>>(wpart, kb2k, sig, den);
    t_reduce<<<dim3(32, 4, 8), 256, 0, stream>>>(KHb, sig, tpart);
    small_gemm<<<dim3(32, 4, 4), 256, 0, stream>>>(tpart, kw2k, kb2k, den, agg);
  }

  final_out<<<16384, 256, 0, stream>>>(dblf, agg, out);
}